// Round 2
// baseline (140.893 us; speedup 1.0000x reference)
//
#include <hip/hip_runtime.h>

#define NUM_ENT 7
#define DIM_ENT 4
#define H 128            // NEMBED_HALF
#define OUTC (2 * H)     // 256 columns per entity
#define BPB 8            // batch elements per block

typedef float f32x4 __attribute__((ext_vector_type(4)));   // native clang vector
                                                           // (HIP float4 is a class —
                                                           // __builtin_nontemporal_store rejects it)

// Grid = B/BPB = 2048 blocks of 256 threads. Each block computes BOTH the
// rel_emb (cols 128..255) and prop_emb (cols 0..127) for its 8 batch elems.
// (R5 lesson: do NOT parity-split roles across blockIdx — it aliases with
// round-robin workgroup->XCD assignment; merging avoids the question.)
//
// R6/R7 change: the old kernel staged pairwise features in s_feat[8][7][7][5]
// (20-byte stride => 4B alignment => 5x ds_read_b32 per (i,j) pair, ~240
// scalar LDS reads per thread between two barriers). That LDS issue pressure
// was the bottleneck, not HBM. Now each thread loads its 7 entities into
// registers via 7 aligned ds_read_b128 (s_ents row stride 112B = 7*16) and
// recomputes diffs+dist inline (~8 VALU @ 2cyc per pair vs 5 LDS @ ~5.8cyc).
// One barrier, no precompute phase, LDS instrs/thread ~240 -> 7.
//
// Within a block: wave w (0..3), lane l: bb = w*2 + (l>>5), c4 = (l&31)*4.
// Both half-waves run IDENTICAL code (different batch element) — no divergence.
__global__ __launch_bounds__(256) void ace_kernel(
    const float* __restrict__ ctx,     // [28, B]
    const float* __restrict__ w_prop,  // [4, 128]
    const float* __restrict__ b_prop,  // [128]
    const float* __restrict__ w_rel,   // [5, 128]
    const float* __restrict__ b_rel,   // [128]
    float* __restrict__ out,           // [B, 7, 256]
    int B)
{
    __shared__ float s_ents[BPB][NUM_ENT * DIM_ENT];          // 8 x 28 floats

    const int tid = threadIdx.x;
    const int b0 = blockIdx.x * BPB;

    // Stage ents, b-fastest for coalescing: tid -> (k = tid>>3, bb = tid&7)
    if (tid < BPB * NUM_ENT * DIM_ENT) {                      // 224 threads
        const int k  = tid >> 3;
        const int bb = tid & 7;
        s_ents[bb][k] = ctx[(size_t)k * B + (b0 + bb)];
    }
    __syncthreads();

    const int w    = tid >> 6;
    const int lane = tid & 63;
    const int bb   = w * 2 + (lane >> 5);
    const int c4   = (lane & 31) << 2;
    float* outb = out + (size_t)(b0 + bb) * (NUM_ENT * OUTC);

    // All 7 entities of this thread's batch element -> registers.
    // s_ents[bb] base = bb*112B (16B aligned), each entity is 16B -> b128.
    f32x4 e[NUM_ENT];
#pragma unroll
    for (int n = 0; n < NUM_ENT; ++n)
        e[n] = *(const f32x4*)(&s_ents[bb][n * DIM_ENT]);

    {   // ---- prop_emb: relu(ents @ w_prop + b_prop) -> cols c4
        const f32x4 w0 = *(const f32x4*)(w_prop + 0 * H + c4);
        const f32x4 w1 = *(const f32x4*)(w_prop + 1 * H + c4);
        const f32x4 w2 = *(const f32x4*)(w_prop + 2 * H + c4);
        const f32x4 w3 = *(const f32x4*)(w_prop + 3 * H + c4);
        const f32x4 bp = *(const f32x4*)(b_prop + c4);
#pragma unroll
        for (int n = 0; n < NUM_ENT; ++n) {
            const float e0 = e[n].x, e1 = e[n].y, e2 = e[n].z, e3 = e[n].w;
            f32x4 a;
            a.x = fmaxf(bp.x + e0 * w0.x + e1 * w1.x + e2 * w2.x + e3 * w3.x, 0.f);
            a.y = fmaxf(bp.y + e0 * w0.y + e1 * w1.y + e2 * w2.y + e3 * w3.y, 0.f);
            a.z = fmaxf(bp.z + e0 * w0.z + e1 * w1.z + e2 * w2.z + e3 * w3.z, 0.f);
            a.w = fmaxf(bp.w + e0 * w0.w + e1 * w1.w + e2 * w2.w + e3 * w3.w, 0.f);
            __builtin_nontemporal_store(a, (f32x4*)(outb + n * OUTC + c4));
        }
    }

    {   // ---- rel_emb: sum_{j!=i} relu(feat(i,j) @ w_rel + b_rel) -> cols 128+c4
        const f32x4 w0 = *(const f32x4*)(w_rel + 0 * H + c4);
        const f32x4 w1 = *(const f32x4*)(w_rel + 1 * H + c4);
        const f32x4 w2 = *(const f32x4*)(w_rel + 2 * H + c4);
        const f32x4 w3 = *(const f32x4*)(w_rel + 3 * H + c4);
        const f32x4 w4 = *(const f32x4*)(w_rel + 4 * H + c4);
        const f32x4 br = *(const f32x4*)(b_rel + c4);
#pragma unroll
        for (int i = 0; i < NUM_ENT; ++i) {
            f32x4 acc = {0.f, 0.f, 0.f, 0.f};
#pragma unroll
            for (int j = 0; j < NUM_ENT; ++j) {
                if (j == i) continue;
                const float dx = e[i].x - e[j].x;
                const float dy = e[i].y - e[j].y;
                const float dz = e[i].z - e[j].z;
                const float dv = e[i].w - e[j].w;
                const float d  = __builtin_amdgcn_sqrtf(dx * dx + dy * dy);
                acc.x += fmaxf(br.x + dx * w0.x + dy * w1.x + dz * w2.x + dv * w3.x + d * w4.x, 0.f);
                acc.y += fmaxf(br.y + dx * w0.y + dy * w1.y + dz * w2.y + dv * w3.y + d * w4.y, 0.f);
                acc.z += fmaxf(br.z + dx * w0.z + dy * w1.z + dz * w2.z + dv * w3.z + d * w4.z, 0.f);
                acc.w += fmaxf(br.w + dx * w0.w + dy * w1.w + dz * w2.w + dv * w3.w + d * w4.w, 0.f);
            }
            __builtin_nontemporal_store(acc, (f32x4*)(outb + i * OUTC + H + c4));
        }
    }
}

extern "C" void kernel_launch(void* const* d_in, const int* in_sizes, int n_in,
                              void* d_out, int out_size, void* d_ws, size_t ws_size,
                              hipStream_t stream) {
    const float* ctx    = (const float*)d_in[0];
    const float* w_prop = (const float*)d_in[1];
    const float* b_prop = (const float*)d_in[2];
    const float* w_rel  = (const float*)d_in[3];
    const float* b_rel  = (const float*)d_in[4];
    float* out = (float*)d_out;

    const int B = in_sizes[0] / (NUM_ENT * DIM_ENT);   // 16384
    const int nb = (B + BPB - 1) / BPB;                // 2048 blocks
    ace_kernel<<<nb, 256, 0, stream>>>(ctx, w_prop, b_prop, w_rel, b_rel, out, B);
}

// Round 3
// 129.708 us; speedup vs baseline: 1.0862x; 1.0862x over previous
//
#include <hip/hip_runtime.h>

#define NUM_ENT 7
#define DIM_ENT 4
#define H 128            // NEMBED_HALF
#define OUTC (2 * H)     // 256 columns per entity
#define BPB 16           // batch elements per block (R8: was 8)

typedef float f32x4 __attribute__((ext_vector_type(4)));   // native clang vector
                                                           // (HIP float4 is a class)

// R8: 8-columns-per-thread layout. 16 threads per batch element (sub=tid&15),
// each owning cols {sub*4, sub*4+64} in both the prop (0..127) and rel
// (128..255) sections. Grid = B/16 = 1024 blocks x 256 threads = 4096 waves
// (4/SIMD at ~110 VGPR). Rationale from R7 post-mortem: LDS-vs-register
// feature staging was a wash (both ~same time; bank conflicts were 0 —
// broadcasts are free), so the lever is total issued instructions: widening
// col/thread 4->8 halves the cross-lane-redundant diff+sqrt work (computed
// once per 16 lanes instead of once per 32... i.e. by half as many threads)
// and halves per-output weight-load/addressing overhead. ~12% fewer issue
// slots grid-wide. Also reverts nontemporal->plain stores (nt was the only
// other delta vs the best 132.6 config and coincided with +5 us).
//
// Store coalescing: per store instruction, a 16-lane group (one batch elem)
// writes 16 x 16 B at stride 16 B = contiguous 256 B (two full 128 B lines),
// because the two quads per thread are split q*64 cols apart rather than
// adjacent.
__global__ __launch_bounds__(256) void ace_kernel(
    const float* __restrict__ ctx,     // [28, B]
    const float* __restrict__ w_prop,  // [4, 128]
    const float* __restrict__ b_prop,  // [128]
    const float* __restrict__ w_rel,   // [5, 128]
    const float* __restrict__ b_rel,   // [128]
    float* __restrict__ out,           // [B, 7, 256]
    int B)
{
    __shared__ float s_ents[BPB][NUM_ENT * DIM_ENT];          // 16 x 28 floats

    const int tid = threadIdx.x;
    const int b0 = blockIdx.x * BPB;

    // Stage ents, bb-fastest for coalescing: t -> (k = t>>4, bb = t&15).
    // 448 elems over 256 threads -> 2 iterations (second half-masked).
#pragma unroll
    for (int t = tid; t < BPB * NUM_ENT * DIM_ENT; t += 256) {
        const int k  = t >> 4;
        const int bb = t & 15;
        s_ents[bb][k] = ctx[(size_t)k * B + (b0 + bb)];
    }
    __syncthreads();

    const int sub = tid & 15;          // column-group within batch elem
    const int bb  = tid >> 4;          // batch elem within block (0..15)
    const int c0  = sub << 2;          // quad 0: cols c0..c0+3
    // quad 1: cols c0+64..c0+67
    float* outb = out + (size_t)(b0 + bb) * (NUM_ENT * OUTC);

    // 7 entities -> registers. s_ents row stride 112 B; within a wave the 4
    // bb-groups read rows at byte offsets {0,112,224,336}+w*448 -> bank
    // windows {0-3,28-31,24-27,20-23}: disjoint, conflict-free; 16 lanes per
    // group share an address (broadcast, free).
    f32x4 e[NUM_ENT];
#pragma unroll
    for (int n = 0; n < NUM_ENT; ++n)
        e[n] = *(const f32x4*)(&s_ents[bb][n * DIM_ENT]);

    {   // ---- prop_emb: relu(ents @ w_prop + b_prop) -> cols {c0, c0+64}
        f32x4 wp[DIM_ENT][2], bp[2];
#pragma unroll
        for (int f = 0; f < DIM_ENT; ++f) {
            wp[f][0] = *(const f32x4*)(w_prop + f * H + c0);
            wp[f][1] = *(const f32x4*)(w_prop + f * H + c0 + 64);
        }
        bp[0] = *(const f32x4*)(b_prop + c0);
        bp[1] = *(const f32x4*)(b_prop + c0 + 64);
#pragma unroll
        for (int n = 0; n < NUM_ENT; ++n) {
            const float e0 = e[n].x, e1 = e[n].y, e2 = e[n].z, e3 = e[n].w;
#pragma unroll
            for (int q = 0; q < 2; ++q) {
                f32x4 a = bp[q];
                a += e0 * wp[0][q];
                a += e1 * wp[1][q];
                a += e2 * wp[2][q];
                a += e3 * wp[3][q];
                a.x = fmaxf(a.x, 0.f); a.y = fmaxf(a.y, 0.f);
                a.z = fmaxf(a.z, 0.f); a.w = fmaxf(a.w, 0.f);
                *(f32x4*)(outb + n * OUTC + c0 + q * 64) = a;
            }
        }
    }

    {   // ---- rel_emb: sum_{j!=i} relu(feat(i,j) @ w_rel + b_rel)
        //      -> cols {128+c0, 128+c0+64}
        f32x4 wr[DIM_ENT + 1][2], br[2];
#pragma unroll
        for (int f = 0; f < DIM_ENT + 1; ++f) {
            wr[f][0] = *(const f32x4*)(w_rel + f * H + c0);
            wr[f][1] = *(const f32x4*)(w_rel + f * H + c0 + 64);
        }
        br[0] = *(const f32x4*)(b_rel + c0);
        br[1] = *(const f32x4*)(b_rel + c0 + 64);
#pragma unroll
        for (int i = 0; i < NUM_ENT; ++i) {
            f32x4 acc0 = {0.f, 0.f, 0.f, 0.f};
            f32x4 acc1 = {0.f, 0.f, 0.f, 0.f};
#pragma unroll
            for (int j = 0; j < NUM_ENT; ++j) {
                if (j == i) continue;
                const float dx = e[i].x - e[j].x;
                const float dy = e[i].y - e[j].y;
                const float dz = e[i].z - e[j].z;
                const float dv = e[i].w - e[j].w;
                const float d  = __builtin_amdgcn_sqrtf(dx * dx + dy * dy);
                {
                    f32x4 t = br[0];
                    t += dx * wr[0][0]; t += dy * wr[1][0]; t += dz * wr[2][0];
                    t += dv * wr[3][0]; t += d  * wr[4][0];
                    acc0.x += fmaxf(t.x, 0.f); acc0.y += fmaxf(t.y, 0.f);
                    acc0.z += fmaxf(t.z, 0.f); acc0.w += fmaxf(t.w, 0.f);
                }
                {
                    f32x4 t = br[1];
                    t += dx * wr[0][1]; t += dy * wr[1][1]; t += dz * wr[2][1];
                    t += dv * wr[3][1]; t += d  * wr[4][1];
                    acc1.x += fmaxf(t.x, 0.f); acc1.y += fmaxf(t.y, 0.f);
                    acc1.z += fmaxf(t.z, 0.f); acc1.w += fmaxf(t.w, 0.f);
                }
            }
            *(f32x4*)(outb + i * OUTC + H + c0)      = acc0;
            *(f32x4*)(outb + i * OUTC + H + c0 + 64) = acc1;
        }
    }
}

extern "C" void kernel_launch(void* const* d_in, const int* in_sizes, int n_in,
                              void* d_out, int out_size, void* d_ws, size_t ws_size,
                              hipStream_t stream) {
    const float* ctx    = (const float*)d_in[0];
    const float* w_prop = (const float*)d_in[1];
    const float* b_prop = (const float*)d_in[2];
    const float* w_rel  = (const float*)d_in[3];
    const float* b_rel  = (const float*)d_in[4];
    float* out = (float*)d_out;

    const int B = in_sizes[0] / (NUM_ENT * DIM_ENT);   // 16384
    const int nb = (B + BPB - 1) / BPB;                // 1024 blocks
    ace_kernel<<<nb, 256, 0, stream>>>(ctx, w_prop, b_prop, w_rel, b_rel, out, B);
}